// Round 6
// baseline (4952.420 us; speedup 1.0000x reference)
//
#include <hip/hip_runtime.h>

// Eikonal 3D — fast-iterative-method (FIM) solver, equivalent fixed point to
// 288 Jacobi Godunov sweeps (monotone min-update, unique maximal fixed point
// below u0; the reference's 288 sweeps are fully converged, tolerance 0.5).
//
// u lives in-place in d_out. 216 tiles of 16^3; per-tile active flags
// ping-pong in d_ws. Per dispatch, a block whose tile or face-neighbor is
// active stages tile+halo(1) into LDS, runs alternating-direction
// Gauss-Seidel z-march sweeps until locally converged (change flag), writes
// back, sets its out-flag. Stale halo / racy reads are monotone-safe (values
// only decrease; flags force re-processing until global quiescence).

#define N      96
#define BIGV   1e5f
#define SRC_IDX ((48 * N + 48) * N + 48)

#define TS     16
#define NT     (N / TS)            // 6
#define NTILES (NT * NT * NT)      // 216
#define IN     (TS + 2)            // 18
#define IN2    (IN * IN)           // 324
#define IN3    (IN * IN * IN)      // 5832
#define TS3    (TS * TS * TS)      // 4096
#define KMAX   40                  // max local sweeps per dispatch
#define CHK    2                   // convergence check every CHK sweeps
#define NDISP  40                  // dispatches (tile-BFS radius 9 + reactivation margin)
#define SRC_TILE (3 * NT * NT + 3 * NT + 3)   // tile (3,3,3)

__global__ __launch_bounds__(256) void eik_init(float* __restrict__ u,
                                                int* __restrict__ flagsA) {
    int idx = blockIdx.x * 256 + threadIdx.x;
    u[idx] = (idx == SRC_IDX) ? 0.0f : BIGV;
    if (blockIdx.x == 0 && threadIdx.x < NTILES)
        flagsA[threadIdx.x] = (threadIdx.x == SRC_TILE) ? 1 : 0;
}

// One Godunov update. zn = min of z-neighbors; (xm,xp),(ym,yp) axis pairs.
// Exact early-out: all candidates are >= lo, so lo >= uc (or all-BIG)
// cannot improve uc. Otherwise identical formula/selection to the reference.
__device__ __forceinline__ float god_update(float zn, float xm, float xp,
                                            float ym, float yp,
                                            float fh, float uc) {
    float b = fminf(xm, xp);
    float c = fminf(ym, yp);
    float a = zn;
    float lo = fminf(fminf(a, b), c);
    if (lo >= BIGV || lo >= uc) return uc;

    float hi  = fmaxf(fmaxf(a, b), c);
    float mid = a + b + c - lo - hi;
    float u1  = lo + fh;
    float cand;
    if (u1 <= mid) {
        cand = u1;
    } else {
        float dlm = lo - mid;
        float d2  = 2.0f * fh * fh - dlm * dlm;
        float u2  = (d2 > 0.0f) ? 0.5f * (lo + mid + sqrtf(d2)) : BIGV;
        if (u2 <= hi) {
            cand = u2;
        } else {
            float s  = lo + mid + hi;
            float qq = lo * lo + mid * mid + hi * hi - fh * fh;
            float d3 = s * s - 3.0f * qq;
            cand = (d3 > 0.0f) ? (s + sqrtf(d3)) / 3.0f : BIGV;
        }
    }
    return fminf(uc, cand);
}

__global__ __launch_bounds__(256) void eik_fim(float* __restrict__ u,
                                               const float* __restrict__ f,
                                               const int* __restrict__ fin,
                                               int* __restrict__ fout) {
    __shared__ float su[IN3];      // 23328 B
    __shared__ float sf[TS3];      // 16384 B
    __shared__ int s_act;
    __shared__ int s_chg;

    const int bid = blockIdx.x;
    const int tx = threadIdx.x, ty = threadIdx.y;
    const int tid = ty * TS + tx;
    const int bx = bid % NT, by = (bid / NT) % NT, bz = bid / (NT * NT);

    if (tid == 0) {
        int a = fin[bid];
        if (bx > 0)      a |= fin[bid - 1];
        if (bx < NT - 1) a |= fin[bid + 1];
        if (by > 0)      a |= fin[bid - NT];
        if (by < NT - 1) a |= fin[bid + NT];
        if (bz > 0)      a |= fin[bid - NT * NT];
        if (bz < NT - 1) a |= fin[bid + NT * NT];
        s_act = a;
        s_chg = 0;
    }
    __syncthreads();
    if (!s_act) { if (tid == 0) fout[bid] = 0; return; }

    const int gx0 = bx * TS - 1, gy0 = by * TS - 1, gz0 = bz * TS - 1;

    // stage u tile + halo (BIG outside domain)
    for (int idx = tid; idx < IN3; idx += 256) {
        int lz = idx / IN2, rem = idx - lz * IN2;
        int ly = rem / IN,  lx = rem - ly * IN;
        int gx = gx0 + lx, gy = gy0 + ly, gz = gz0 + lz;
        bool ins = ((unsigned)gx < N) & ((unsigned)gy < N) & ((unsigned)gz < N);
        su[idx] = ins ? u[(gz * N + gy) * N + gx] : BIGV;
    }
    // stage f interior (tiles partition the domain exactly)
    {
        const int fx0 = bx * TS, fy0 = by * TS, fz0 = bz * TS;
        for (int idx = tid; idx < TS3; idx += 256) {
            int lz = idx >> 8, ly = (idx >> 4) & 15, lx = idx & 15;
            sf[idx] = f[((fz0 + lz) * N + fy0 + ly) * N + fx0 + lx];
        }
    }
    __syncthreads();

    const int coff = (ty + 1) * IN + (tx + 1);   // this thread's column
    int any_change = 0;

    for (int s = 0; s < KMAX; ++s) {
        int changed = 0;
        if ((s & 1) == 0) {                      // ascending z march
            float um = su[coff];                 // z=0 halo
            float uc = su[IN2 + coff];
            #pragma unroll
            for (int zi = 1; zi <= TS; ++zi) {
                const int li = zi * IN2 + coff;
                float up = su[li + IN2];
                float xm = su[li - 1],  xp = su[li + 1];
                float ym = su[li - IN], yp = su[li + IN];
                float fh = sf[(zi - 1) * (TS * TS) + tid];
                float v  = god_update(fminf(um, up), xm, xp, ym, yp, fh, uc);
                if (v < uc) { su[li] = v; changed = 1; }
                um = v; uc = up;
            }
        } else {                                 // descending z march
            float up = su[(TS + 1) * IN2 + coff];
            float uc = su[TS * IN2 + coff];
            #pragma unroll
            for (int zi = TS; zi >= 1; --zi) {
                const int li = zi * IN2 + coff;
                float um = su[li - IN2];
                float xm = su[li - 1],  xp = su[li + 1];
                float ym = su[li - IN], yp = su[li + IN];
                float fh = sf[(zi - 1) * (TS * TS) + tid];
                float v  = god_update(fminf(um, up), xm, xp, ym, yp, fh, uc);
                if (v < uc) { su[li] = v; changed = 1; }
                up = v; uc = um;
            }
        }
        if (changed) s_chg = 1;                  // sticky, benign race
        if ((s & (CHK - 1)) == (CHK - 1)) {
            __syncthreads();                     // all s_chg writes visible
            int c = s_chg;
            __syncthreads();                     // all reads done
            if (tid == 0) s_chg = 0;
            __syncthreads();                     // reset visible before next writes
            if (!c) break;
            any_change = 1;
        }
    }
    __syncthreads();                             // final LDS state visible

    if (any_change) {
        #pragma unroll
        for (int zi = 1; zi <= TS; ++zi) {
            int gz = gz0 + zi;
            u[(gz * N + (gy0 + ty + 1)) * N + (gx0 + tx + 1)] = su[zi * IN2 + coff];
        }
    }
    if (tid == 0) fout[bid] = any_change;
}

extern "C" void kernel_launch(void* const* d_in, const int* in_sizes, int n_in,
                              void* d_out, int out_size, void* d_ws, size_t ws_size,
                              hipStream_t stream) {
    const float* f = (const float*)d_in[0];
    float* u = (float*)d_out;            // solved in place
    int* flagsA = (int*)d_ws;            // 216 ints
    int* flagsB = flagsA + 256;          // 216 ints (padded offset)

    eik_init<<<(N * N * N) / 256, 256, 0, stream>>>(u, flagsA);

    for (int d = 0; d < NDISP; ++d) {
        const int* fi = (d & 1) ? flagsB : flagsA;
        int*       fo = (d & 1) ? flagsA : flagsB;
        eik_fim<<<NTILES, dim3(TS, TS), 0, stream>>>(u, f, fi, fo);
    }
}

// Round 7
// 4826.721 us; speedup vs baseline: 1.0260x; 1.0260x over previous
//
#include <hip/hip_runtime.h>

// Eikonal 3D — FIM solver, fixed point identical to 288 Jacobi Godunov sweeps
// (monotone min-update; reference is fully converged; validated in R6).
// Round 7: latency fix — own z-column + f held in REGISTERS (full unroll,
// static indices); LDS only for neighbor exchange. Per z-step: 4 independent
// ds_reads + <=1 ds_write nothing waits on; loop-carried dep = ALU only.
//
// u in-place in d_out. 216 tiles of 16^3; active flags ping-pong in d_ws.
// Chaotic in-place updates are monotone-safe; flags force re-processing
// until global quiescence.

#define N      96
#define BIGV   1e5f
#define SRC_IDX ((48 * N + 48) * N + 48)

#define TS     16
#define NT     (N / TS)            // 6
#define NTILES (NT * NT * NT)      // 216
#define IN     (TS + 2)            // 18
#define IN2    (IN * IN)           // 324
#define IN3    (IN * IN * IN)      // 5832
#define KMAX   40                  // max local sweeps per dispatch
#define CHK    2                   // convergence check every CHK sweeps
#define NDISP  32
#define SRC_TILE (3 * NT * NT + 3 * NT + 3)

__global__ __launch_bounds__(256) void eik_init(float* __restrict__ u,
                                                int* __restrict__ flagsA) {
    int idx = blockIdx.x * 256 + threadIdx.x;
    u[idx] = (idx == SRC_IDX) ? 0.0f : BIGV;
    if (blockIdx.x == 0 && threadIdx.x < NTILES)
        flagsA[threadIdx.x] = (threadIdx.x == SRC_TILE) ? 1 : 0;
}

// Godunov update; a = min of z-neighbors. Early-out is exact: all candidates
// are >= lo, so lo >= uc implies min(uc, cand) == uc (also covers uc==0 at
// the pinned source and the all-BIG region).
__device__ __forceinline__ float god_update(float a, float xm, float xp,
                                            float ym, float yp,
                                            float fh, float uc) {
    float b = fminf(xm, xp);
    float c = fminf(ym, yp);
    float lo = fminf(fminf(a, b), c);
    if (lo >= uc) return uc;

    float hi  = fmaxf(fmaxf(a, b), c);
    float mid = a + b + c - lo - hi;
    float u1  = lo + fh;
    float cand;
    if (u1 <= mid) {
        cand = u1;
    } else {
        float dlm = lo - mid;
        float d2  = 2.0f * fh * fh - dlm * dlm;
        float u2  = (d2 > 0.0f) ? 0.5f * (lo + mid + sqrtf(d2)) : BIGV;
        if (u2 <= hi) {
            cand = u2;
        } else {
            float s  = lo + mid + hi;
            float qq = lo * lo + mid * mid + hi * hi - fh * fh;
            float d3 = s * s - 3.0f * qq;
            cand = (d3 > 0.0f) ? (s + sqrtf(d3)) / 3.0f : BIGV;
        }
    }
    return fminf(uc, cand);
}

__global__ __launch_bounds__(256) void eik_fim(float* __restrict__ u,
                                               const float* __restrict__ f,
                                               const int* __restrict__ fin,
                                               int* __restrict__ fout) {
    __shared__ float su[IN3];      // 23328 B
    __shared__ int s_act;
    __shared__ int s_chg;

    const int bid = blockIdx.x;
    const int tx = threadIdx.x, ty = threadIdx.y;
    const int tid = ty * TS + tx;
    const int bx = bid % NT, by = (bid / NT) % NT, bz = bid / (NT * NT);

    if (tid == 0) {
        int a = fin[bid];
        if (bx > 0)      a |= fin[bid - 1];
        if (bx < NT - 1) a |= fin[bid + 1];
        if (by > 0)      a |= fin[bid - NT];
        if (by < NT - 1) a |= fin[bid + NT];
        if (bz > 0)      a |= fin[bid - NT * NT];
        if (bz < NT - 1) a |= fin[bid + NT * NT];
        s_act = a;
        s_chg = 0;
    }
    __syncthreads();
    if (!s_act) { if (tid == 0) fout[bid] = 0; return; }

    const int gx0 = bx * TS - 1, gy0 = by * TS - 1, gz0 = bz * TS - 1;

    // ---- stage u tile + halo into LDS (BIG outside domain) ----
    for (int idx = tid; idx < IN3; idx += 256) {
        int lz = idx / IN2, rem = idx - lz * IN2;
        int ly = rem / IN,  lx = rem - ly * IN;
        int gx = gx0 + lx, gy = gy0 + ly, gz = gz0 + lz;
        bool ins = ((unsigned)gx < N) & ((unsigned)gy < N) & ((unsigned)gz < N);
        su[idx] = ins ? u[(gz * N + gy) * N + gx] : BIGV;
    }
    __syncthreads();

    const int gx = gx0 + tx + 1;              // this thread's column
    const int gy = gy0 + ty + 1;
    const int coff = (ty + 1) * IN + (tx + 1);

    // ---- own column + slowness in registers (static indices only) ----
    float uz[TS + 2];                         // [0] and [TS+1] are z-halos
    float fz[TS];
    #pragma unroll
    for (int zi = 0; zi <= TS + 1; ++zi) uz[zi] = su[zi * IN2 + coff];
    #pragma unroll
    for (int zi = 0; zi < TS; ++zi)
        fz[zi] = f[((gz0 + zi + 1) * N + gy) * N + gx];

    int any_change = 0;

    for (int s = 0; s < KMAX; ++s) {
        int changed = 0;
        if ((s & 1) == 0) {                   // ascending z (GS downward dep)
            float um = uz[0];
            #pragma unroll
            for (int zi = 1; zi <= TS; ++zi) {
                const int li = zi * IN2 + coff;
                float xm = su[li - 1],  xp = su[li + 1];
                float ym = su[li - IN], yp = su[li + IN];
                float uc = uz[zi];
                float v  = god_update(fminf(um, uz[zi + 1]),
                                      xm, xp, ym, yp, fz[zi - 1], uc);
                if (v < uc) { su[li] = v; uz[zi] = v; changed = 1; }
                um = v;
            }
        } else {                              // descending z
            float up = uz[TS + 1];
            #pragma unroll
            for (int zi = TS; zi >= 1; --zi) {
                const int li = zi * IN2 + coff;
                float xm = su[li - 1],  xp = su[li + 1];
                float ym = su[li - IN], yp = su[li + IN];
                float uc = uz[zi];
                float v  = god_update(fminf(uz[zi - 1], up),
                                      xm, xp, ym, yp, fz[zi - 1], uc);
                if (v < uc) { su[li] = v; uz[zi] = v; changed = 1; }
                up = v;
            }
        }
        if (changed) s_chg = 1;               // sticky, benign race
        if ((s & (CHK - 1)) == (CHK - 1)) {
            __syncthreads();                  // s_chg writes visible
            int c = s_chg;
            __syncthreads();                  // reads done
            if (tid == 0) s_chg = 0;
            __syncthreads();                  // reset visible
            if (!c) break;
            any_change = 1;
        }
    }

    if (any_change) {
        #pragma unroll
        for (int zi = 1; zi <= TS; ++zi)
            u[((gz0 + zi) * N + gy) * N + gx] = uz[zi];
    }
    if (tid == 0) fout[bid] = any_change;
}

extern "C" void kernel_launch(void* const* d_in, const int* in_sizes, int n_in,
                              void* d_out, int out_size, void* d_ws, size_t ws_size,
                              hipStream_t stream) {
    const float* f = (const float*)d_in[0];
    float* u = (float*)d_out;            // solved in place
    int* flagsA = (int*)d_ws;
    int* flagsB = flagsA + 256;

    eik_init<<<(N * N * N) / 256, 256, 0, stream>>>(u, flagsA);

    for (int d = 0; d < NDISP; ++d) {
        const int* fi = (d & 1) ? flagsB : flagsA;
        int*       fo = (d & 1) ? flagsA : flagsB;
        eik_fim<<<NTILES, dim3(TS, TS), 0, stream>>>(u, f, fi, fo);
    }
}